// Round 14
// baseline (253.881 us; speedup 1.0000x reference)
//
#include <hip/hip_runtime.h>
#include <math.h>

// flash-decode, GQA paged KV. R=4, B=16, Hq=32, Hk=8 (G=4), D=128, P=8192,
// PAGE=1, M=2048.
// Storage (confirmed round 7): q/k_cache/v_cache FLOAT32; lens/bt int32;
// out float32.
//
// Round 14: uniform work quanta. Every (r,b,hk) is cut into 16 FIXED
// 128-token windows; one wave per window, fully independent (no LDS, no
// barrier). Active waves all do exactly 8 iterations -> straggler tail
// collapses (r13's chunk=kvlen/4 blocks varied 64x in runtime; occupancy
// 25%). Waves past kvlen write a sentinel and exit immediately.

typedef float f32x4 __attribute__((ext_vector_type(4)));

#define R_ 4
#define B_ 16
#define HQ_ 32
#define HK_ 8
#define G_ 4
#define D_ 128
#define P_ 8192
#define M_ 2048
#define HKD (HK_ * D_)
#define NWIN 16   // fixed windows per (r,b,hk)
#define WTOK 128  // tokens per window
#define SC2 (0.08838834764831845f * 1.4426950408889634f)  // scale * log2(e)
#define MNEG (-1.0e30f)

__device__ __forceinline__ void load8u(const float* __restrict__ ubase,
                                       unsigned boff, float o[8]) {
  const f32x4* p = (const f32x4*)((const char*)ubase + boff);
  f32x4 a = p[0];
  f32x4 b = p[1];
#pragma unroll
  for (int j = 0; j < 4; ++j) { o[j] = a[j]; o[4 + j] = b[j]; }
}

__device__ __forceinline__ int clampP(int p) {
  return p < 0 ? 0 : (p >= P_ ? P_ - 1 : p);
}

// ---------------- kernel 1: one wave per (r,b,hk,window) ----------------
__global__ __launch_bounds__(256) void fd_partial(
    const float* __restrict__ q, const float* __restrict__ kc,
    const float* __restrict__ vc, const int* __restrict__ lens,
    const int* __restrict__ bt, float* __restrict__ ws_m,
    float* __restrict__ ws_l, float* __restrict__ ws_o) {
  const int lane = threadIdx.x & 63;
  const int w = threadIdx.x >> 6;
  const int gw = blockIdx.x * 4 + w;  // global wave id == record id
  const int s = gw & (NWIN - 1);
  const int hk = (gw >> 4) & (HK_ - 1);
  const int b = (gw >> 7) & (B_ - 1);
  const int r = gw >> 11;

  const int tg = lane >> 4;        // slot 0..3: 4 contiguous tokens per iter
  const int ds = (lane & 15) * 8;  // dim slice [ds, ds+8)
  const unsigned dsb = ds * 4u;

  int kvlen = lens[r * B_ + b];
  if (kvlen < 0) kvlen = 0;
  if (kvlen > M_) kvlen = M_;
  const int base = s * WTOK;
  if (base >= kvlen) {  // inactive window: sentinel, exit (no barriers)
    if (lane == 0) {
#pragma unroll
      for (int h = 0; h < G_; ++h) ws_m[gw * G_ + h] = MNEG;
    }
    return;
  }
  const int t1 = (base + WTOK < kvlen) ? base + WTOK : kvlen;

  // q fragments for all 4 heads, pre-scaled into log2 domain
  float qf[G_][8];
  {
    const float* qp = q + (size_t)(b * HQ_ + hk * G_) * D_ + ds;
#pragma unroll
    for (int h = 0; h < G_; ++h) {
      load8u(qp + h * D_, 0u, qf[h]);
#pragma unroll
      for (int j = 0; j < 8; ++j) qf[h][j] *= SC2;
    }
  }

  const int* btrow = bt + (r * B_ + b) * M_;
  const float* kb = kc + (size_t)r * P_ * HKD + (size_t)hk * D_;
  const float* vb = vc + (size_t)r * P_ * HKD + (size_t)hk * D_;

  float m[G_], l[G_], acc[G_][8];
#pragma unroll
  for (int h = 0; h < G_; ++h) {
    m[h] = MNEG;
    l[h] = 0.f;
#pragma unroll
    for (int j = 0; j < 8; ++j) acc[h][j] = 0.f;
  }

  const int sstart = base + tg * 4;  // 4-aligned; all 8 iters within window
  int4 pgN = *(const int4*)(btrow + sstart);

#pragma unroll
  for (int i = 0; i < WTOK / 16; ++i) {
    const int4 pg = pgN;
    if (i + 1 < WTOK / 16) pgN = *(const int4*)(btrow + sstart + (i + 1) * 16);
    const unsigned o0 = ((unsigned)clampP(pg.x) << 12) + dsb;
    const unsigned o1 = ((unsigned)clampP(pg.y) << 12) + dsb;
    const unsigned o2 = ((unsigned)clampP(pg.z) << 12) + dsb;
    const unsigned o3 = ((unsigned)clampP(pg.w) << 12) + dsb;

    float k0[8], k1[8], k2[8], k3[8], v0[8], v1[8], v2[8], v3[8];
    load8u(kb, o0, k0);
    load8u(kb, o1, k1);
    load8u(kb, o2, k2);
    load8u(kb, o3, k3);
    load8u(vb, o0, v0);
    load8u(vb, o1, v1);
    load8u(vb, o2, v2);
    load8u(vb, o3, v3);

    float d0[G_], d1[G_], d2[G_], d3[G_];
#pragma unroll
    for (int h = 0; h < G_; ++h) {
      float a0 = 0.f, a1 = 0.f, a2 = 0.f, a3 = 0.f;
#pragma unroll
      for (int j = 0; j < 8; ++j) {
        a0 += qf[h][j] * k0[j];
        a1 += qf[h][j] * k1[j];
        a2 += qf[h][j] * k2[j];
        a3 += qf[h][j] * k3[j];
      }
      d0[h] = a0; d1[h] = a1; d2[h] = a2; d3[h] = a3;
    }
#pragma unroll
    for (int msk = 1; msk <= 8; msk <<= 1) {
#pragma unroll
      for (int h = 0; h < G_; ++h) {
        d0[h] += __shfl_xor(d0[h], msk);
        d1[h] += __shfl_xor(d1[h], msk);
        d2[h] += __shfl_xor(d2[h], msk);
        d3[h] += __shfl_xor(d3[h], msk);
      }
    }

    const int tb = sstart + i * 16;
    const bool va0 = tb < t1;
    const bool va1 = tb + 1 < t1;
    const bool va2 = tb + 2 < t1;
    const bool va3 = tb + 3 < t1;
#pragma unroll
    for (int h = 0; h < G_; ++h) {
      const float s0 = va0 ? d0[h] : -INFINITY;
      const float s1 = va1 ? d1[h] : -INFINITY;
      const float s2 = va2 ? d2[h] : -INFINITY;
      const float s3 = va3 ? d3[h] : -INFINITY;
      const float mt = fmaxf(fmaxf(s0, s1), fmaxf(s2, s3));
      const float mn = fmaxf(m[h], mt);   // finite always (>= MNEG)
      const float sc = exp2f(m[h] - mn);  // branchless, no NaN
      const float p0 = exp2f(s0 - mn);    // -inf -> 0
      const float p1 = exp2f(s1 - mn);
      const float p2 = exp2f(s2 - mn);
      const float p3 = exp2f(s3 - mn);
      m[h] = mn;
      l[h] = l[h] * sc + (p0 + p1) + (p2 + p3);
#pragma unroll
      for (int j = 0; j < 8; ++j)
        acc[h][j] = acc[h][j] * sc + p0 * v0[j] + p1 * v1[j] + p2 * v2[j] +
                    p3 * v3[j];
    }
  }

  // merge the 4 token slots (xor 16, 32), per head — branchless
#pragma unroll
  for (int h = 0; h < G_; ++h) {
#pragma unroll
    for (int off = 16; off <= 32; off <<= 1) {
      const float mo = __shfl_xor(m[h], off);
      const float lo = __shfl_xor(l[h], off);
      float ao[8];
#pragma unroll
      for (int j = 0; j < 8; ++j) ao[j] = __shfl_xor(acc[h][j], off);
      const float mn = fmaxf(m[h], mo);
      const float se = exp2f(m[h] - mn);
      const float so_ = exp2f(mo - mn);
      l[h] = l[h] * se + lo * so_;
#pragma unroll
      for (int j = 0; j < 8; ++j) acc[h][j] = acc[h][j] * se + ao[j] * so_;
      m[h] = mn;
    }
  }

  if (lane < 16) {
#pragma unroll
    for (int h = 0; h < G_; ++h) {
#pragma unroll
      for (int j = 0; j < 8; ++j)
        ws_o[((size_t)gw * G_ + h) * D_ + ds + j] = acc[h][j];
    }
  }
  if (lane == 0) {
#pragma unroll
    for (int h = 0; h < G_; ++h) {
      ws_m[gw * G_ + h] = m[h];  // log2-domain
      ws_l[gw * G_ + h] = l[h];
    }
  }
}

// ---------------- kernel 2: LSE-weighted combine over R*NWIN ----------------
__global__ __launch_bounds__(128) void fd_reduce(
    const float* __restrict__ ws_m, const float* __restrict__ ws_l,
    const float* __restrict__ ws_o, float* __restrict__ out) {
  const int row = blockIdx.x;  // (b*HK + hk)*G + g
  const int g = row % G_;
  const int hk = (row / G_) % HK_;
  const int b = row / (G_ * HK_);
  const int d = threadIdx.x;

  float mf = MNEG;
  for (int r = 0; r < R_; ++r)
    for (int s = 0; s < NWIN; ++s) {
      int rec = ((r * B_ + b) * HK_ + hk) * NWIN + s;
      mf = fmaxf(mf, ws_m[rec * G_ + g]);
    }
  float of = 0.f, lf = 0.f;
  for (int r = 0; r < R_; ++r)
    for (int s = 0; s < NWIN; ++s) {
      int rec = ((r * B_ + b) * HK_ + hk) * NWIN + s;
      float wt = exp2f(ws_m[rec * G_ + g] - mf);  // inactive -> 0
      of += wt * ws_o[((size_t)rec * G_ + g) * D_ + d];
      lf += wt * ws_l[rec * G_ + g];
    }
  out[(size_t)(b * HQ_ + hk * G_ + g) * D_ + d] = of / lf;
}

// ---------------- fallback: monolithic (tiny workspace) ----------------
__global__ __launch_bounds__(256) void fd_mono(
    const float* __restrict__ q, const float* __restrict__ kc,
    const float* __restrict__ vc, const int* __restrict__ lens,
    const int* __restrict__ bt, float* __restrict__ out) {
  const int hk = blockIdx.x % HK_;
  const int b = blockIdx.x / HK_;
  const int lane = threadIdx.x & 63;
  const int g = threadIdx.x >> 6;
  const int tg = lane >> 4;
  const int ds = (lane & 15) * 8;
  const unsigned dsb = ds * 4u;

  float qf[8];
  load8u(q + (size_t)(b * HQ_ + hk * G_ + g) * D_ + ds, 0u, qf);
#pragma unroll
  for (int j = 0; j < 8; ++j) qf[j] *= SC2;

  float m = MNEG, l = 0.f, acc[8];
#pragma unroll
  for (int j = 0; j < 8; ++j) acc[j] = 0.f;

  for (int r = 0; r < R_; ++r) {
    int kvlen = lens[r * B_ + b];
    if (kvlen < 0) kvlen = 0;
    if (kvlen > M_) kvlen = M_;
    const int* btrow = bt + (r * B_ + b) * M_;
    const float* kb = kc + (size_t)r * P_ * HKD + (size_t)hk * D_;
    const float* vb = vc + (size_t)r * P_ * HKD + (size_t)hk * D_;

    for (int t = 0; t < kvlen; t += 4) {
      const int ta = t + tg;
      const bool va = ta < kvlen;
      const unsigned oa = ((unsigned)clampP(btrow[va ? ta : 0]) << 12) + dsb;
      float ka[8], wa[8];
      load8u(kb, oa, ka);
      load8u(vb, oa, wa);

      float da = 0.f;
#pragma unroll
      for (int j = 0; j < 8; ++j) da += qf[j] * ka[j];
#pragma unroll
      for (int msk = 1; msk <= 8; msk <<= 1) da += __shfl_xor(da, msk);

      const float sa = va ? da : -INFINITY;
      const float mn = fmaxf(m, sa);
      const float sc = exp2f(m - mn);
      const float pa = exp2f(sa - mn);
      m = mn;
      l = l * sc + pa;
#pragma unroll
      for (int j = 0; j < 8; ++j) acc[j] = acc[j] * sc + pa * wa[j];
    }
  }

#pragma unroll
  for (int off = 16; off <= 32; off <<= 1) {
    const float mo = __shfl_xor(m, off);
    const float lo = __shfl_xor(l, off);
    float ao[8];
#pragma unroll
    for (int j = 0; j < 8; ++j) ao[j] = __shfl_xor(acc[j], off);
    const float mn = fmaxf(m, mo);
    const float se = exp2f(m - mn);
    const float so_ = exp2f(mo - mn);
    l = l * se + lo * so_;
#pragma unroll
    for (int j = 0; j < 8; ++j) acc[j] = acc[j] * se + ao[j] * so_;
    m = mn;
  }

  if (lane < 16) {
    float inv = (l > 0.f) ? 1.0f / l : 0.f;
#pragma unroll
    for (int j = 0; j < 8; ++j)
      out[(size_t)(b * HQ_ + hk * G_ + g) * D_ + ds + j] = acc[j] * inv;
  }
}

extern "C" void kernel_launch(void* const* d_in, const int* in_sizes, int n_in,
                              void* d_out, int out_size, void* d_ws,
                              size_t ws_size, hipStream_t stream) {
  const float* q = (const float*)d_in[0];
  const float* kc = (const float*)d_in[1];
  const float* vc = (const float*)d_in[2];
  const int* lens = (const int*)d_in[3];
  const int* bt = (const int*)d_in[4];
  float* out = (float*)d_out;

  const int nrec = R_ * B_ * HK_ * NWIN;  // 8192 wave-records
  const size_t need =
      (size_t)nrec * (size_t)(2 * G_ + G_ * D_) * sizeof(float);  // ~17 MB

  if (need <= ws_size) {
    float* ws_m = (float*)d_ws;
    float* ws_l = ws_m + (size_t)nrec * G_;
    float* ws_o = ws_l + (size_t)nrec * G_;
    fd_partial<<<nrec / 4, 256, 0, stream>>>(q, kc, vc, lens, bt, ws_m, ws_l,
                                             ws_o);
    fd_reduce<<<B_ * HK_ * G_, 128, 0, stream>>>(ws_m, ws_l, ws_o, out);
  } else {
    fd_mono<<<B_ * HK_, 256, 0, stream>>>(q, kc, vc, lens, bt, out);
  }
}

// Round 15
// 128.649 us; speedup vs baseline: 1.9734x; 1.9734x over previous
//
#include <hip/hip_runtime.h>
#include <math.h>

// flash-decode, GQA paged KV. R=4, B=16, Hq=32, Hk=8 (G=4), D=128, P=8192,
// PAGE=1, M=2048.
// Storage (confirmed round 7): q/k_cache/v_cache FLOAT32; lens/bt int32;
// out float32.
//
// Round 15 = round-14's uniform-work decomposition (fixed 128-token windows,
// one independent wave per record, sentinel exit, no LDS/barrier) with
// round-13's codegen: `#pragma unroll 1` on the window loop. Round 14's
// full unroll made all 8 iterations' K/V buffers live -> VGPR 252,
// occupancy 6.6%, 297 us. r13's identical body with a dynamic bound was
// VGPR 76. Epilogue writes spread across slots (slot tg writes head tg).

typedef float f32x4 __attribute__((ext_vector_type(4)));

#define R_ 4
#define B_ 16
#define HQ_ 32
#define HK_ 8
#define G_ 4
#define D_ 128
#define P_ 8192
#define M_ 2048
#define HKD (HK_ * D_)
#define NWIN 16   // fixed windows per (r,b,hk)
#define WTOK 128  // tokens per window
#define SC2 (0.08838834764831845f * 1.4426950408889634f)  // scale * log2(e)
#define MNEG (-1.0e30f)

__device__ __forceinline__ void load8u(const float* __restrict__ ubase,
                                       unsigned boff, float o[8]) {
  const f32x4* p = (const f32x4*)((const char*)ubase + boff);
  f32x4 a = p[0];
  f32x4 b = p[1];
#pragma unroll
  for (int j = 0; j < 4; ++j) { o[j] = a[j]; o[4 + j] = b[j]; }
}

__device__ __forceinline__ int clampP(int p) {
  return p < 0 ? 0 : (p >= P_ ? P_ - 1 : p);
}

// ---------------- kernel 1: one wave per (r,b,hk,window) ----------------
__global__ __launch_bounds__(256) void fd_partial(
    const float* __restrict__ q, const float* __restrict__ kc,
    const float* __restrict__ vc, const int* __restrict__ lens,
    const int* __restrict__ bt, float* __restrict__ ws_m,
    float* __restrict__ ws_l, float* __restrict__ ws_o) {
  const int lane = threadIdx.x & 63;
  const int w = threadIdx.x >> 6;
  const int gw = blockIdx.x * 4 + w;  // global wave id == record id
  const int s = gw & (NWIN - 1);
  const int hk = (gw >> 4) & (HK_ - 1);
  const int b = (gw >> 7) & (B_ - 1);
  const int r = gw >> 11;

  const int tg = lane >> 4;        // slot 0..3: 4 contiguous tokens per iter
  const int ds = (lane & 15) * 8;  // dim slice [ds, ds+8)
  const unsigned dsb = ds * 4u;

  int kvlen = lens[r * B_ + b];
  if (kvlen < 0) kvlen = 0;
  if (kvlen > M_) kvlen = M_;
  const int base = s * WTOK;
  if (base >= kvlen) {  // inactive window: sentinel, exit
    if (lane == 0) {
#pragma unroll
      for (int h = 0; h < G_; ++h) ws_m[gw * G_ + h] = MNEG;
    }
    return;
  }
  const int t1 = (base + WTOK < kvlen) ? base + WTOK : kvlen;

  // q fragments for all 4 heads, pre-scaled into log2 domain
  float qf[G_][8];
  {
    const float* qp = q + (size_t)(b * HQ_ + hk * G_) * D_ + ds;
#pragma unroll
    for (int h = 0; h < G_; ++h) {
      load8u(qp + h * D_, 0u, qf[h]);
#pragma unroll
      for (int j = 0; j < 8; ++j) qf[h][j] *= SC2;
    }
  }

  const int* btrow = bt + (r * B_ + b) * M_;
  const float* kb = kc + (size_t)r * P_ * HKD + (size_t)hk * D_;
  const float* vb = vc + (size_t)r * P_ * HKD + (size_t)hk * D_;

  float m[G_], l[G_], acc[G_][8];
#pragma unroll
  for (int h = 0; h < G_; ++h) {
    m[h] = MNEG;
    l[h] = 0.f;
#pragma unroll
    for (int j = 0; j < 8; ++j) acc[h][j] = 0.f;
  }

  const int sstart = base + tg * 4;  // 4-aligned
  int4 pgN = *(const int4*)(btrow + sstart);

#pragma unroll 1
  for (int i = 0; i < WTOK / 16; ++i) {
    const int4 pg = pgN;
    if (i + 1 < WTOK / 16) pgN = *(const int4*)(btrow + sstart + (i + 1) * 16);
    const unsigned o0 = ((unsigned)clampP(pg.x) << 12) + dsb;
    const unsigned o1 = ((unsigned)clampP(pg.y) << 12) + dsb;
    const unsigned o2 = ((unsigned)clampP(pg.z) << 12) + dsb;
    const unsigned o3 = ((unsigned)clampP(pg.w) << 12) + dsb;

    float k0[8], k1[8], k2[8], k3[8], v0[8], v1[8], v2[8], v3[8];
    load8u(kb, o0, k0);
    load8u(kb, o1, k1);
    load8u(kb, o2, k2);
    load8u(kb, o3, k3);
    load8u(vb, o0, v0);
    load8u(vb, o1, v1);
    load8u(vb, o2, v2);
    load8u(vb, o3, v3);

    float d0[G_], d1[G_], d2[G_], d3[G_];
#pragma unroll
    for (int h = 0; h < G_; ++h) {
      float a0 = 0.f, a1 = 0.f, a2 = 0.f, a3 = 0.f;
#pragma unroll
      for (int j = 0; j < 8; ++j) {
        a0 += qf[h][j] * k0[j];
        a1 += qf[h][j] * k1[j];
        a2 += qf[h][j] * k2[j];
        a3 += qf[h][j] * k3[j];
      }
      d0[h] = a0; d1[h] = a1; d2[h] = a2; d3[h] = a3;
    }
#pragma unroll
    for (int msk = 1; msk <= 8; msk <<= 1) {
#pragma unroll
      for (int h = 0; h < G_; ++h) {
        d0[h] += __shfl_xor(d0[h], msk);
        d1[h] += __shfl_xor(d1[h], msk);
        d2[h] += __shfl_xor(d2[h], msk);
        d3[h] += __shfl_xor(d3[h], msk);
      }
    }

    const int tb = sstart + i * 16;
    const bool va0 = tb < t1;
    const bool va1 = tb + 1 < t1;
    const bool va2 = tb + 2 < t1;
    const bool va3 = tb + 3 < t1;
#pragma unroll
    for (int h = 0; h < G_; ++h) {
      const float s0 = va0 ? d0[h] : -INFINITY;
      const float s1 = va1 ? d1[h] : -INFINITY;
      const float s2 = va2 ? d2[h] : -INFINITY;
      const float s3 = va3 ? d3[h] : -INFINITY;
      const float mt = fmaxf(fmaxf(s0, s1), fmaxf(s2, s3));
      const float mn = fmaxf(m[h], mt);   // finite always (>= MNEG)
      const float sc = exp2f(m[h] - mn);  // branchless, no NaN
      const float p0 = exp2f(s0 - mn);    // -inf -> 0
      const float p1 = exp2f(s1 - mn);
      const float p2 = exp2f(s2 - mn);
      const float p3 = exp2f(s3 - mn);
      m[h] = mn;
      l[h] = l[h] * sc + (p0 + p1) + (p2 + p3);
#pragma unroll
      for (int j = 0; j < 8; ++j)
        acc[h][j] = acc[h][j] * sc + p0 * v0[j] + p1 * v1[j] + p2 * v2[j] +
                    p3 * v3[j];
    }
  }

  // merge the 4 token slots (xor 16, 32), per head — branchless
#pragma unroll
  for (int h = 0; h < G_; ++h) {
#pragma unroll
    for (int off = 16; off <= 32; off <<= 1) {
      const float mo = __shfl_xor(m[h], off);
      const float lo = __shfl_xor(l[h], off);
      float ao[8];
#pragma unroll
      for (int j = 0; j < 8; ++j) ao[j] = __shfl_xor(acc[h][j], off);
      const float mn = fmaxf(m[h], mo);
      const float se = exp2f(m[h] - mn);
      const float so_ = exp2f(mo - mn);
      l[h] = l[h] * se + lo * so_;
#pragma unroll
      for (int j = 0; j < 8; ++j) acc[h][j] = acc[h][j] * se + ao[j] * so_;
      m[h] = mn;
    }
  }

  // after merge all 4 slots hold identical state: slot tg writes head tg
  {
    float* wp = ws_o + ((size_t)gw * G_ + tg) * D_ + ds;
    if (tg == 0) {
#pragma unroll
      for (int j = 0; j < 8; ++j) wp[j] = acc[0][j];
    } else if (tg == 1) {
#pragma unroll
      for (int j = 0; j < 8; ++j) wp[j] = acc[1][j];
    } else if (tg == 2) {
#pragma unroll
      for (int j = 0; j < 8; ++j) wp[j] = acc[2][j];
    } else {
#pragma unroll
      for (int j = 0; j < 8; ++j) wp[j] = acc[3][j];
    }
  }
  if (lane == 0) {
#pragma unroll
    for (int h = 0; h < G_; ++h) {
      ws_m[gw * G_ + h] = m[h];  // log2-domain
      ws_l[gw * G_ + h] = l[h];
    }
  }
}

// ---------------- kernel 2: LSE-weighted combine over R*NWIN ----------------
__global__ __launch_bounds__(128) void fd_reduce(
    const float* __restrict__ ws_m, const float* __restrict__ ws_l,
    const float* __restrict__ ws_o, float* __restrict__ out) {
  const int row = blockIdx.x;  // (b*HK + hk)*G + g
  const int g = row % G_;
  const int hk = (row / G_) % HK_;
  const int b = row / (G_ * HK_);
  const int d = threadIdx.x;

  float mf = MNEG;
  for (int r = 0; r < R_; ++r)
    for (int s = 0; s < NWIN; ++s) {
      int rec = ((r * B_ + b) * HK_ + hk) * NWIN + s;
      mf = fmaxf(mf, ws_m[rec * G_ + g]);
    }
  float of = 0.f, lf = 0.f;
  for (int r = 0; r < R_; ++r)
    for (int s = 0; s < NWIN; ++s) {
      int rec = ((r * B_ + b) * HK_ + hk) * NWIN + s;
      float wt = exp2f(ws_m[rec * G_ + g] - mf);  // inactive -> 0
      of += wt * ws_o[((size_t)rec * G_ + g) * D_ + d];
      lf += wt * ws_l[rec * G_ + g];
    }
  out[(size_t)(b * HQ_ + hk * G_ + g) * D_ + d] = of / lf;
}

// ---------------- fallback: monolithic (tiny workspace) ----------------
__global__ __launch_bounds__(256) void fd_mono(
    const float* __restrict__ q, const float* __restrict__ kc,
    const float* __restrict__ vc, const int* __restrict__ lens,
    const int* __restrict__ bt, float* __restrict__ out) {
  const int hk = blockIdx.x % HK_;
  const int b = blockIdx.x / HK_;
  const int lane = threadIdx.x & 63;
  const int g = threadIdx.x >> 6;
  const int tg = lane >> 4;
  const int ds = (lane & 15) * 8;
  const unsigned dsb = ds * 4u;

  float qf[8];
  load8u(q + (size_t)(b * HQ_ + hk * G_ + g) * D_ + ds, 0u, qf);
#pragma unroll
  for (int j = 0; j < 8; ++j) qf[j] *= SC2;

  float m = MNEG, l = 0.f, acc[8];
#pragma unroll
  for (int j = 0; j < 8; ++j) acc[j] = 0.f;

  for (int r = 0; r < R_; ++r) {
    int kvlen = lens[r * B_ + b];
    if (kvlen < 0) kvlen = 0;
    if (kvlen > M_) kvlen = M_;
    const int* btrow = bt + (r * B_ + b) * M_;
    const float* kb = kc + (size_t)r * P_ * HKD + (size_t)hk * D_;
    const float* vb = vc + (size_t)r * P_ * HKD + (size_t)hk * D_;

#pragma unroll 1
    for (int t = 0; t < kvlen; t += 4) {
      const int ta = t + tg;
      const bool va = ta < kvlen;
      const unsigned oa = ((unsigned)clampP(btrow[va ? ta : 0]) << 12) + dsb;
      float ka[8], wa[8];
      load8u(kb, oa, ka);
      load8u(vb, oa, wa);

      float da = 0.f;
#pragma unroll
      for (int j = 0; j < 8; ++j) da += qf[j] * ka[j];
#pragma unroll
      for (int msk = 1; msk <= 8; msk <<= 1) da += __shfl_xor(da, msk);

      const float sa = va ? da : -INFINITY;
      const float mn = fmaxf(m, sa);
      const float sc = exp2f(m - mn);
      const float pa = exp2f(sa - mn);
      m = mn;
      l = l * sc + pa;
#pragma unroll
      for (int j = 0; j < 8; ++j) acc[j] = acc[j] * sc + pa * wa[j];
    }
  }

#pragma unroll
  for (int off = 16; off <= 32; off <<= 1) {
    const float mo = __shfl_xor(m, off);
    const float lo = __shfl_xor(l, off);
    float ao[8];
#pragma unroll
    for (int j = 0; j < 8; ++j) ao[j] = __shfl_xor(acc[j], off);
    const float mn = fmaxf(m, mo);
    const float se = exp2f(m - mn);
    const float so_ = exp2f(mo - mn);
    l = l * se + lo * so_;
#pragma unroll
    for (int j = 0; j < 8; ++j) acc[j] = acc[j] * se + ao[j] * so_;
    m = mn;
  }

  if (lane < 16) {
    float inv = (l > 0.f) ? 1.0f / l : 0.f;
#pragma unroll
    for (int j = 0; j < 8; ++j)
      out[(size_t)(b * HQ_ + hk * G_ + g) * D_ + ds + j] = acc[j] * inv;
  }
}

extern "C" void kernel_launch(void* const* d_in, const int* in_sizes, int n_in,
                              void* d_out, int out_size, void* d_ws,
                              size_t ws_size, hipStream_t stream) {
  const float* q = (const float*)d_in[0];
  const float* kc = (const float*)d_in[1];
  const float* vc = (const float*)d_in[2];
  const int* lens = (const int*)d_in[3];
  const int* bt = (const int*)d_in[4];
  float* out = (float*)d_out;

  const int nrec = R_ * B_ * HK_ * NWIN;  // 8192 wave-records
  const size_t need =
      (size_t)nrec * (size_t)(2 * G_ + G_ * D_) * sizeof(float);  // ~17 MB

  if (need <= ws_size) {
    float* ws_m = (float*)d_ws;
    float* ws_l = ws_m + (size_t)nrec * G_;
    float* ws_o = ws_l + (size_t)nrec * G_;
    fd_partial<<<nrec / 4, 256, 0, stream>>>(q, kc, vc, lens, bt, ws_m, ws_l,
                                             ws_o);
    fd_reduce<<<B_ * HK_ * G_, 128, 0, stream>>>(ws_m, ws_l, ws_o, out);
  } else {
    fd_mono<<<B_ * HK_, 256, 0, stream>>>(q, kc, vc, lens, bt, out);
  }
}